// Round 8
// baseline (125.344 us; speedup 1.0000x reference)
//
#include <hip/hip_runtime.h>

// KANLayer: B=1024, I=64, O=64, H=32. ALL I/O float32 (per reference).
// out[b,o] = sum_i [ bw[o,i]*leaky(x[b,i]) + lw[o,i]*( sum_k W3[o,i,k]*h2[k] + b3[o,i] ) ]
//   h1[h] = leaky(x[b,i]*W1[o,i,h] + b1[o,i,h])
//   h2[k] = leaky(sum_h h1[h]*W2[o,i,k,h] + b2[o,i,k])
//
// R8 = R7 body, reshaped for occupancy: 512-thread blocks (8 waves), each
// wave owns an i-slice of 8 and all 4 m-tiles (64 rows). Grid 1024 blocks
// (o-fastest) -> 4 blocks/CU x 8 waves = 32 waves/CU = 8 waves/SIMD (2x R7)
// to hide the W2 L2-load latency R6/R7 stalled on. W2 L2 traffic unchanged.
// mfma_f32_16x16x32_f16, f32 accum, b2 folded into C, epilogue leaky via
// abs-modifier identity. launch_bounds(512,8) caps VGPR at 64.

#define H_   32
#define NI   64
#define NO   64
#define NB   1024
#define ROWS 64     // batch rows per block
#define XSTR 66     // x LDS row stride (uint pairs): 8B-aligned, 2-way banks (free)
#define NWAVE 8

typedef float    floatx4 __attribute__((ext_vector_type(4)));
typedef _Float16 halfx8  __attribute__((ext_vector_type(8)));
typedef _Float16 halfx2  __attribute__((ext_vector_type(2)));

union H8 { halfx8 v8; halfx2 v2[4]; unsigned int u[4]; };

__device__ inline float leaky(float v) { return fmaxf(v, 0.01f * v); }

__device__ inline unsigned int pkrtz(float a, float b) {   // (a,b) -> f16x2, RTZ
    return __builtin_bit_cast(unsigned int, __builtin_amdgcn_cvt_pkrtz(a, b));
}

__global__ __launch_bounds__(512, 8)
void kan_kernel(const float* __restrict__ x,  const float* __restrict__ W1,
                const float* __restrict__ b1, const float* __restrict__ W2,
                const float* __restrict__ b2, const float* __restrict__ W3,
                const float* __restrict__ b3, const float* __restrict__ lw,
                const float* __restrict__ bw, float* __restrict__ out)
{
    __shared__ unsigned int xsp[ROWS * XSTR];  // x dup-f16 pairs, 16.9 KB
    __shared__ _Float16 w1s[NI * H_];          // 4 KB
    __shared__ _Float16 b1s[NI * H_];          // 4 KB
    __shared__ unsigned int wbs[NI * H_];      // {lw*w3, b2} f16 pairs, 8 KB
    __shared__ float rc[ROWS];
    __shared__ float part[NWAVE][ROWS];        // per-wave i-slice partials, 2 KB

    const int t    = threadIdx.x;
    const int o    = blockIdx.x;               // o fastest -> same-o blocks share XCD
    const int row0 = blockIdx.y * ROWS;

    // ---- stage x tile as duplicated f16 pairs (512 thr x 8 floats) ----
    const float* xsrc = x + (size_t)row0 * NI;
    #pragma unroll
    for (int v = 0; v < 2; ++v) {
        int fe = (v * 512 + t) * 4;            // multiple of 4
        int r = fe >> 6, c = fe & 63;
        float4 xv = *(const float4*)(xsrc + fe);
        uint2 lo = { pkrtz(xv.x, xv.x), pkrtz(xv.y, xv.y) };
        uint2 hi = { pkrtz(xv.z, xv.z), pkrtz(xv.w, xv.w) };
        *(uint2*)(&xsp[r * XSTR + c])     = lo;   // 66r+c even -> 8B aligned
        *(uint2*)(&xsp[r * XSTR + c + 2]) = hi;
    }
    // ---- stage W1/b1 for this o as f16 (512 thr x 4 elems) ----
    const float* w1g = W1 + (size_t)o * NI * H_;
    const float* b1g = b1 + (size_t)o * NI * H_;
    {
        int e = t * 4;
        float4 a = *(const float4*)(w1g + e);
        float4 c = *(const float4*)(b1g + e);
        uint2 pa = { pkrtz(a.x, a.y), pkrtz(a.z, a.w) };
        uint2 pc = { pkrtz(c.x, c.y), pkrtz(c.z, c.w) };
        *(uint2*)(w1s + e) = pa;
        *(uint2*)(b1s + e) = pc;
    }
    // ---- stage {lw*w3, b2} pairs: 2048 entries, 4 per thread ----
    {
        int e = t * 4;                          // i = e>>5, k = e&31 .. +3
        float l = lw[o * NI + (e >> 5)];
        const float* w3g = W3 + (size_t)o * NI * H_ + e;
        const float* b2g = b2 + (size_t)o * NI * H_ + e;
        float4 wa = *(const float4*)(w3g);
        float4 ba = *(const float4*)(b2g);
        uint4 p0 = { pkrtz(l * wa.x, ba.x), pkrtz(l * wa.y, ba.y),
                     pkrtz(l * wa.z, ba.z), pkrtz(l * wa.w, ba.w) };
        *(uint4*)(&wbs[e]) = p0;
    }
    __syncthreads();

    // ---- per-row constants: rc[r] = sum_i [ bw*leaky(x) + lw*b3 ] ----
    if (t < ROWS) {
        float s = 0.f;
        const float* bwp = bw + o * NI;
        const float* lp  = lw + o * NI;
        const float* b3p = b3 + o * NI;
        for (int i = 0; i < NI; ++i) {
            halfx2 hx = __builtin_bit_cast(halfx2, xsp[t * XSTR + i]);
            s += bwp[i] * leaky((float)hx[0]) + lp[i] * b3p[i];
        }
        rc[t] = s;
    }

    const int lane = t & 63, wave = t >> 6;
    const int col  = lane & 15;            // MFMA n-index (h2 k-slot) / A m-offset
    const int kh   = lane >> 4;            // contraction quad
    const int koff = kh * 8;
    const int i0   = wave * 8;             // this wave's i-slice (8 wide)

    const float* w2p0 = W2 + ((size_t)(o * NI + i0) * H_ + col) * H_ + koff;
    const float* w2p1 = w2p0 + 16 * H_;
    const halfx2 slope = { (_Float16)0.01f, (_Float16)0.01f };

    floatx4 pacc[4] = { {0,0,0,0}, {0,0,0,0}, {0,0,0,0}, {0,0,0,0} };

    #pragma unroll 2
    for (int ii = 0; ii < 8; ++ii) {
        const int i = i0 + ii;

        // B-frags: W2[o,i, col(+16), koff..+7], f32 -> f16 via pkrtz
        floatx4 a0 = *(const floatx4*)(w2p0);
        floatx4 a1 = *(const floatx4*)(w2p0 + 4);
        floatx4 a2 = *(const floatx4*)(w2p1);
        floatx4 a3 = *(const floatx4*)(w2p1 + 4);
        H8 bf0, bf1;
        bf0.u[0] = pkrtz(a0[0], a0[1]);  bf0.u[1] = pkrtz(a0[2], a0[3]);
        bf0.u[2] = pkrtz(a1[0], a1[1]);  bf0.u[3] = pkrtz(a1[2], a1[3]);
        bf1.u[0] = pkrtz(a2[0], a2[1]);  bf1.u[1] = pkrtz(a2[2], a2[3]);
        bf1.u[2] = pkrtz(a3[0], a3[1]);  bf1.u[3] = pkrtz(a3[2], a3[3]);

        H8 w1v, b1v;
        w1v.v8 = *(const halfx8*)(w1s + i * H_ + koff);
        b1v.v8 = *(const halfx8*)(b1s + i * H_ + koff);

        // per-k constants from LDS: {lw*w3, b2} f16 pairs (broadcast reads)
        halfx2 q0 = __builtin_bit_cast(halfx2, wbs[i * H_ + col]);
        halfx2 q1 = __builtin_bit_cast(halfx2, wbs[i * H_ + col + 16]);
        float w3e0 = (float)q0[0], b2c0 = (float)q0[1];
        float w3e1 = (float)q1[0], b2c1 = (float)q1[1];
        float p0 = 0.505f * w3e0, n0 = 0.495f * w3e0;   // leaky decomposition
        float p1 = 0.505f * w3e1, n1 = 0.495f * w3e1;

        #pragma unroll
        for (int m = 0; m < 4; ++m) {
            halfx2 xx = __builtin_bit_cast(halfx2, xsp[(m * 16 + col) * XSTR + i]);
            H8 af;
            #pragma unroll
            for (int j = 0; j < 4; ++j) {
                halfx2 h = __builtin_elementwise_fma(xx, w1v.v2[j], b1v.v2[j]);
                af.v2[j] = __builtin_elementwise_max(h, h * slope);  // pk leaky
            }
            floatx4 c0 = { b2c0, b2c0, b2c0, b2c0 };   // b2 folded into C
            floatx4 c1 = { b2c1, b2c1, b2c1, b2c1 };
            c0 = __builtin_amdgcn_mfma_f32_16x16x32_f16(af.v8, bf0.v8, c0, 0, 0, 0);
            c1 = __builtin_amdgcn_mfma_f32_16x16x32_f16(af.v8, bf1.v8, c1, 0, 0, 0);
            // pacc += leaky(c)*w3e : leaky(v)*w = (.505w)*v + (.495w)*|v|
            #pragma unroll
            for (int r = 0; r < 4; ++r) {
                pacc[m][r] = fmaf(p0, c0[r],
                             fmaf(n0, fabsf(c0[r]),
                             fmaf(p1, c1[r],
                             fmaf(n1, fabsf(c1[r]), pacc[m][r]))));
            }
        }

        w2p0 += H_ * H_;  w2p1 += H_ * H_;
    }

    // ---- in-wave reduce over the 16 col lanes, deposit i-slice partials ----
    #pragma unroll
    for (int m = 0; m < 4; ++m) {
        #pragma unroll
        for (int r = 0; r < 4; ++r) {
            float v = pacc[m][r];
            v += __shfl_xor(v, 1, 64);
            v += __shfl_xor(v, 2, 64);
            v += __shfl_xor(v, 4, 64);
            v += __shfl_xor(v, 8, 64);
            if (col == 0)
                part[wave][m * 16 + kh * 4 + r] = v;   // C row = (lane>>4)*4+reg
        }
    }
    __syncthreads();

    // ---- cross-wave sum + per-row constant, write out[b,o] ----
    if (t < ROWS) {
        float v = rc[t];
        #pragma unroll
        for (int w = 0; w < NWAVE; ++w) v += part[w][t];
        out[(size_t)(row0 + t) * NO + o] = v;
    }
}

extern "C" void kernel_launch(void* const* d_in, const int* in_sizes, int n_in,
                              void* d_out, int out_size, void* d_ws, size_t ws_size,
                              hipStream_t stream) {
    const float* x  = (const float*)d_in[0];
    const float* W1 = (const float*)d_in[1];
    const float* b1 = (const float*)d_in[2];
    const float* W2 = (const float*)d_in[3];
    const float* b2 = (const float*)d_in[4];
    const float* W3 = (const float*)d_in[5];
    const float* b3 = (const float*)d_in[6];
    const float* lw = (const float*)d_in[7];
    const float* bw = (const float*)d_in[8];
    float* out = (float*)d_out;

    dim3 grid(NO, NB / ROWS);   // 1024 blocks, o fastest (XCD-local W2)
    kan_kernel<<<grid, dim3(512), 0, stream>>>(x, W1, b1, W2, b2, W3, b3, lw, bw, out);
}

// Round 9
// 115.444 us; speedup vs baseline: 1.0858x; 1.0858x over previous
//
#include <hip/hip_runtime.h>

// KANLayer: B=1024, I=64, O=64, H=32. ALL I/O float32 (per reference).
// out[b,o] = sum_i [ bw[o,i]*leaky(x[b,i]) + lw[o,i]*( sum_k W3[o,i,k]*h2[k] + b3[o,i] ) ]
//   h1[h] = leaky(x[b,i]*W1[o,i,h] + b1[o,i,h])
//   h2[k] = leaky(sum_h h1[h]*W2[o,i,k,h] + b2[o,i,k])
//
// R9 = R8 structure (512-thread blocks, 8 waves, wave w owns i-slice
// [w*8, w*8+8), all 4 m-tiles), but __launch_bounds__(512, 6):
// R8's (512,8) squeezed the ~52-VGPR body into 32 VGPRs -> scratch spills
// (WRITE_SIZE 2->52 MB, the regression). (512,6) gives an ~85-VGPR budget:
// no spills, 6 waves/SIMD resident (1.5x R7) to hide W2 L2 latency.
// mfma_f32_16x16x32_f16, f32 accum, b2 folded into C, epilogue leaky via
// abs-modifier identity. Grid o-fastest: W2 slab XCD-L2-resident.

#define H_   32
#define NI   64
#define NO   64
#define NB   1024
#define ROWS 64     // batch rows per block
#define XSTR 66     // x LDS row stride (uint pairs): 8B-aligned, 2-way banks (free)
#define NWAVE 8

typedef float    floatx4 __attribute__((ext_vector_type(4)));
typedef _Float16 halfx8  __attribute__((ext_vector_type(8)));
typedef _Float16 halfx2  __attribute__((ext_vector_type(2)));

union H8 { halfx8 v8; halfx2 v2[4]; unsigned int u[4]; };

__device__ inline float leaky(float v) { return fmaxf(v, 0.01f * v); }

__device__ inline unsigned int pkrtz(float a, float b) {   // (a,b) -> f16x2, RTZ
    return __builtin_bit_cast(unsigned int, __builtin_amdgcn_cvt_pkrtz(a, b));
}

__global__ __launch_bounds__(512, 6)
void kan_kernel(const float* __restrict__ x,  const float* __restrict__ W1,
                const float* __restrict__ b1, const float* __restrict__ W2,
                const float* __restrict__ b2, const float* __restrict__ W3,
                const float* __restrict__ b3, const float* __restrict__ lw,
                const float* __restrict__ bw, float* __restrict__ out)
{
    __shared__ unsigned int xsp[ROWS * XSTR];  // x dup-f16 pairs, 16.9 KB
    __shared__ _Float16 w1s[NI * H_];          // 4 KB
    __shared__ _Float16 b1s[NI * H_];          // 4 KB
    __shared__ unsigned int wbs[NI * H_];      // {lw*w3, b2} f16 pairs, 8 KB
    __shared__ float rc[ROWS];
    __shared__ float part[NWAVE][ROWS];        // per-wave i-slice partials, 2 KB

    const int t    = threadIdx.x;
    const int o    = blockIdx.x;               // o fastest -> same-o blocks share XCD
    const int row0 = blockIdx.y * ROWS;

    // ---- stage x tile as duplicated f16 pairs (512 thr x 8 floats) ----
    const float* xsrc = x + (size_t)row0 * NI;
    #pragma unroll
    for (int v = 0; v < 2; ++v) {
        int fe = (v * 512 + t) * 4;            // multiple of 4
        int r = fe >> 6, c = fe & 63;
        float4 xv = *(const float4*)(xsrc + fe);
        uint2 lo = { pkrtz(xv.x, xv.x), pkrtz(xv.y, xv.y) };
        uint2 hi = { pkrtz(xv.z, xv.z), pkrtz(xv.w, xv.w) };
        *(uint2*)(&xsp[r * XSTR + c])     = lo;   // 66r+c even -> 8B aligned
        *(uint2*)(&xsp[r * XSTR + c + 2]) = hi;
    }
    // ---- stage W1/b1 for this o as f16 (512 thr x 4 elems) ----
    const float* w1g = W1 + (size_t)o * NI * H_;
    const float* b1g = b1 + (size_t)o * NI * H_;
    {
        int e = t * 4;
        float4 a = *(const float4*)(w1g + e);
        float4 c = *(const float4*)(b1g + e);
        uint2 pa = { pkrtz(a.x, a.y), pkrtz(a.z, a.w) };
        uint2 pc = { pkrtz(c.x, c.y), pkrtz(c.z, c.w) };
        *(uint2*)(w1s + e) = pa;
        *(uint2*)(b1s + e) = pc;
    }
    // ---- stage {lw*w3, b2} pairs: 2048 entries, 4 per thread ----
    {
        int e = t * 4;                          // i = e>>5, k = e&31 .. +3
        float l = lw[o * NI + (e >> 5)];
        const float* w3g = W3 + (size_t)o * NI * H_ + e;
        const float* b2g = b2 + (size_t)o * NI * H_ + e;
        float4 wa = *(const float4*)(w3g);
        float4 ba = *(const float4*)(b2g);
        uint4 p0 = { pkrtz(l * wa.x, ba.x), pkrtz(l * wa.y, ba.y),
                     pkrtz(l * wa.z, ba.z), pkrtz(l * wa.w, ba.w) };
        *(uint4*)(&wbs[e]) = p0;
    }
    __syncthreads();

    // ---- per-row constants: rc[r] = sum_i [ bw*leaky(x) + lw*b3 ] ----
    if (t < ROWS) {
        float s = 0.f;
        const float* bwp = bw + o * NI;
        const float* lp  = lw + o * NI;
        const float* b3p = b3 + o * NI;
        for (int i = 0; i < NI; ++i) {
            halfx2 hx = __builtin_bit_cast(halfx2, xsp[t * XSTR + i]);
            s += bwp[i] * leaky((float)hx[0]) + lp[i] * b3p[i];
        }
        rc[t] = s;
    }

    const int lane = t & 63, wave = t >> 6;
    const int col  = lane & 15;            // MFMA n-index (h2 k-slot) / A m-offset
    const int kh   = lane >> 4;            // contraction quad
    const int koff = kh * 8;
    const int i0   = wave * 8;             // this wave's i-slice (8 wide)

    const float* w2p0 = W2 + ((size_t)(o * NI + i0) * H_ + col) * H_ + koff;
    const float* w2p1 = w2p0 + 16 * H_;
    const halfx2 slope = { (_Float16)0.01f, (_Float16)0.01f };

    floatx4 pacc[4] = { {0,0,0,0}, {0,0,0,0}, {0,0,0,0}, {0,0,0,0} };

    #pragma unroll 2
    for (int ii = 0; ii < 8; ++ii) {
        const int i = i0 + ii;

        // B-frags: W2[o,i, col(+16), koff..+7], f32 -> f16 via pkrtz
        floatx4 a0 = *(const floatx4*)(w2p0);
        floatx4 a1 = *(const floatx4*)(w2p0 + 4);
        floatx4 a2 = *(const floatx4*)(w2p1);
        floatx4 a3 = *(const floatx4*)(w2p1 + 4);
        H8 bf0, bf1;
        bf0.u[0] = pkrtz(a0[0], a0[1]);  bf0.u[1] = pkrtz(a0[2], a0[3]);
        bf0.u[2] = pkrtz(a1[0], a1[1]);  bf0.u[3] = pkrtz(a1[2], a1[3]);
        bf1.u[0] = pkrtz(a2[0], a2[1]);  bf1.u[1] = pkrtz(a2[2], a2[3]);
        bf1.u[2] = pkrtz(a3[0], a3[1]);  bf1.u[3] = pkrtz(a3[2], a3[3]);

        H8 w1v, b1v;
        w1v.v8 = *(const halfx8*)(w1s + i * H_ + koff);
        b1v.v8 = *(const halfx8*)(b1s + i * H_ + koff);

        // per-k constants from LDS: {lw*w3, b2} f16 pairs (broadcast reads)
        halfx2 q0 = __builtin_bit_cast(halfx2, wbs[i * H_ + col]);
        halfx2 q1 = __builtin_bit_cast(halfx2, wbs[i * H_ + col + 16]);
        float w3e0 = (float)q0[0], b2c0 = (float)q0[1];
        float w3e1 = (float)q1[0], b2c1 = (float)q1[1];
        float p0 = 0.505f * w3e0, n0 = 0.495f * w3e0;   // leaky decomposition
        float p1 = 0.505f * w3e1, n1 = 0.495f * w3e1;

        #pragma unroll
        for (int m = 0; m < 4; ++m) {
            halfx2 xx = __builtin_bit_cast(halfx2, xsp[(m * 16 + col) * XSTR + i]);
            H8 af;
            #pragma unroll
            for (int j = 0; j < 4; ++j) {
                halfx2 h = __builtin_elementwise_fma(xx, w1v.v2[j], b1v.v2[j]);
                af.v2[j] = __builtin_elementwise_max(h, h * slope);  // pk leaky
            }
            floatx4 c0 = { b2c0, b2c0, b2c0, b2c0 };   // b2 folded into C
            floatx4 c1 = { b2c1, b2c1, b2c1, b2c1 };
            c0 = __builtin_amdgcn_mfma_f32_16x16x32_f16(af.v8, bf0.v8, c0, 0, 0, 0);
            c1 = __builtin_amdgcn_mfma_f32_16x16x32_f16(af.v8, bf1.v8, c1, 0, 0, 0);
            // pacc += leaky(c)*w3e : leaky(v)*w = (.505w)*v + (.495w)*|v|
            #pragma unroll
            for (int r = 0; r < 4; ++r) {
                pacc[m][r] = fmaf(p0, c0[r],
                             fmaf(n0, fabsf(c0[r]),
                             fmaf(p1, c1[r],
                             fmaf(n1, fabsf(c1[r]), pacc[m][r]))));
            }
        }

        w2p0 += H_ * H_;  w2p1 += H_ * H_;
    }

    // ---- in-wave reduce over the 16 col lanes, deposit i-slice partials ----
    #pragma unroll
    for (int m = 0; m < 4; ++m) {
        #pragma unroll
        for (int r = 0; r < 4; ++r) {
            float v = pacc[m][r];
            v += __shfl_xor(v, 1, 64);
            v += __shfl_xor(v, 2, 64);
            v += __shfl_xor(v, 4, 64);
            v += __shfl_xor(v, 8, 64);
            if (col == 0)
                part[wave][m * 16 + kh * 4 + r] = v;   // C row = (lane>>4)*4+reg
        }
    }
    __syncthreads();

    // ---- cross-wave sum + per-row constant, write out[b,o] ----
    if (t < ROWS) {
        float v = rc[t];
        #pragma unroll
        for (int w = 0; w < NWAVE; ++w) v += part[w][t];
        out[(size_t)(row0 + t) * NO + o] = v;
    }
}

extern "C" void kernel_launch(void* const* d_in, const int* in_sizes, int n_in,
                              void* d_out, int out_size, void* d_ws, size_t ws_size,
                              hipStream_t stream) {
    const float* x  = (const float*)d_in[0];
    const float* W1 = (const float*)d_in[1];
    const float* b1 = (const float*)d_in[2];
    const float* W2 = (const float*)d_in[3];
    const float* b2 = (const float*)d_in[4];
    const float* W3 = (const float*)d_in[5];
    const float* b3 = (const float*)d_in[6];
    const float* lw = (const float*)d_in[7];
    const float* bw = (const float*)d_in[8];
    float* out = (float*)d_out;

    dim3 grid(NO, NB / ROWS);   // 1024 blocks, o fastest (XCD-local W2)
    kan_kernel<<<grid, dim3(512), 0, stream>>>(x, W1, b1, W2, b2, W3, b3, lw, bw, out);
}

// Round 11
// 114.620 us; speedup vs baseline: 1.0936x; 1.0072x over previous
//
#include <hip/hip_runtime.h>

// KANLayer: B=1024, I=64, O=64, H=32. ALL I/O float32 (per reference).
// out[b,o] = sum_i [ bw[o,i]*leaky(x[b,i]) + lw[o,i]*( sum_k W3[o,i,k]*h2[k] + b3[o,i] ) ]
//   h1[h] = leaky(x[b,i]*W1[o,i,h] + b1[o,i,h])
//   h2[k] = leaky(sum_h h1[h]*W2[o,i,k,h] + b2[o,i,k])
//
// R11 = R10 with the compile bug fixed (floatx4 pacc[MT], not [MT][4]).
// Empirical law R5->R9: time ~ W2-fragment-iterations per CU (1024->132us,
// 256->47us). ROWS=128 (8 m-tiles/wave, 16 MFMA per W2 fragment), 512-thr
// blocks, wave w owns i-slice [w*8,w*8+8). Explicit next-iter W2 register
// prefetch. launch_bounds(512,4): VGPR budget 128, no spills (R8 lesson).
// Grid 512 blocks (o-fastest) = 2/CU, 16 waves/CU. LDS 53.5 KB.
// mfma_f32_16x16x32_f16, f32 accum, b2 folded into C, epilogue leaky via
// abs-modifier identity (leaky(v)*w = .505w*v + .495w*|v|).

#define H_   32
#define NI   64
#define NO   64
#define NB   1024
#define ROWS 128    // batch rows per block (8 m-tiles)
#define MT   8      // m-tiles per wave
#define XSTR 66     // x LDS row stride (uint pairs): 8B-aligned, 2-way banks (free)
#define NWAVE 8

typedef float    floatx4 __attribute__((ext_vector_type(4)));
typedef _Float16 halfx8  __attribute__((ext_vector_type(8)));
typedef _Float16 halfx2  __attribute__((ext_vector_type(2)));

union H8 { halfx8 v8; halfx2 v2[4]; unsigned int u[4]; };

__device__ inline float leaky(float v) { return fmaxf(v, 0.01f * v); }

__device__ inline unsigned int pkrtz(float a, float b) {   // (a,b) -> f16x2, RTZ
    return __builtin_bit_cast(unsigned int, __builtin_amdgcn_cvt_pkrtz(a, b));
}

__global__ __launch_bounds__(512, 4)
void kan_kernel(const float* __restrict__ x,  const float* __restrict__ W1,
                const float* __restrict__ b1, const float* __restrict__ W2,
                const float* __restrict__ b2, const float* __restrict__ W3,
                const float* __restrict__ b3, const float* __restrict__ lw,
                const float* __restrict__ bw, float* __restrict__ out)
{
    __shared__ unsigned int xsp[ROWS * XSTR];  // x dup-f16 pairs, 33.8 KB
    __shared__ _Float16 w1s[NI * H_];          // 4 KB
    __shared__ _Float16 b1s[NI * H_];          // 4 KB
    __shared__ unsigned int wbs[NI * H_];      // {lw*w3, b2} f16 pairs, 8 KB
    __shared__ float rc[ROWS];                 // 512 B
    __shared__ float part[NWAVE][ROWS];        // per-wave i-slice partials, 4 KB

    const int t    = threadIdx.x;
    const int o    = blockIdx.x;               // o fastest -> same-o blocks share XCD
    const int row0 = blockIdx.y * ROWS;

    // ---- stage x tile as duplicated f16 pairs (512 thr x 16 floats) ----
    const float* xsrc = x + (size_t)row0 * NI;
    #pragma unroll
    for (int v = 0; v < 4; ++v) {
        int fe = (v * 512 + t) * 4;            // multiple of 4
        int r = fe >> 6, c = fe & 63;
        float4 xv = *(const float4*)(xsrc + fe);
        uint2 lo = { pkrtz(xv.x, xv.x), pkrtz(xv.y, xv.y) };
        uint2 hi = { pkrtz(xv.z, xv.z), pkrtz(xv.w, xv.w) };
        *(uint2*)(&xsp[r * XSTR + c])     = lo;   // 66r+c even -> 8B aligned
        *(uint2*)(&xsp[r * XSTR + c + 2]) = hi;
    }
    // ---- stage W1/b1 for this o as f16 (512 thr x 4 elems) ----
    const float* w1g = W1 + (size_t)o * NI * H_;
    const float* b1g = b1 + (size_t)o * NI * H_;
    {
        int e = t * 4;
        float4 a = *(const float4*)(w1g + e);
        float4 c = *(const float4*)(b1g + e);
        uint2 pa = { pkrtz(a.x, a.y), pkrtz(a.z, a.w) };
        uint2 pc = { pkrtz(c.x, c.y), pkrtz(c.z, c.w) };
        *(uint2*)(w1s + e) = pa;
        *(uint2*)(b1s + e) = pc;
    }
    // ---- stage {lw*w3, b2} pairs: 2048 entries, 4 per thread ----
    {
        int e = t * 4;                          // i = e>>5, k = e&31 .. +3
        float l = lw[o * NI + (e >> 5)];
        const float* w3g = W3 + (size_t)o * NI * H_ + e;
        const float* b2g = b2 + (size_t)o * NI * H_ + e;
        float4 wa = *(const float4*)(w3g);
        float4 ba = *(const float4*)(b2g);
        uint4 p0 = { pkrtz(l * wa.x, ba.x), pkrtz(l * wa.y, ba.y),
                     pkrtz(l * wa.z, ba.z), pkrtz(l * wa.w, ba.w) };
        *(uint4*)(&wbs[e]) = p0;
    }
    __syncthreads();

    // ---- per-row constants: rc[r] = sum_i [ bw*leaky(x) + lw*b3 ] ----
    if (t < ROWS) {
        float s = 0.f;
        const float* bwp = bw + o * NI;
        const float* lp  = lw + o * NI;
        const float* b3p = b3 + o * NI;
        for (int i = 0; i < NI; ++i) {
            halfx2 hx = __builtin_bit_cast(halfx2, xsp[t * XSTR + i]);
            s += bwp[i] * leaky((float)hx[0]) + lp[i] * b3p[i];
        }
        rc[t] = s;
    }

    const int lane = t & 63, wave = t >> 6;
    const int col  = lane & 15;            // MFMA n-index (h2 k-slot) / A m-offset
    const int kh   = lane >> 4;            // contraction quad
    const int koff = kh * 8;
    const int i0   = wave * 8;             // this wave's i-slice (8 wide)

    const float* w2p0 = W2 + ((size_t)(o * NI + i0) * H_ + col) * H_ + koff;
    const float* w2p1 = w2p0 + 16 * H_;
    const halfx2 slope = { (_Float16)0.01f, (_Float16)0.01f };

    floatx4 pacc[MT];
    #pragma unroll
    for (int m = 0; m < MT; ++m)
        pacc[m] = floatx4{0.f, 0.f, 0.f, 0.f};

    // prime the prefetch registers with iter 0's W2 fragment
    floatx4 a0 = *(const floatx4*)(w2p0);
    floatx4 a1 = *(const floatx4*)(w2p0 + 4);
    floatx4 a2 = *(const floatx4*)(w2p1);
    floatx4 a3 = *(const floatx4*)(w2p1 + 4);

    #pragma unroll 2
    for (int ii = 0; ii < 8; ++ii) {
        const int i = i0 + ii;

        // issue next iteration's W2 loads before consuming this one's
        floatx4 n0, n1, n2, n3;
        if (ii < 7) {
            const float* np0 = w2p0 + (ii + 1) * (H_ * H_);
            const float* np1 = w2p1 + (ii + 1) * (H_ * H_);
            n0 = *(const floatx4*)(np0);
            n1 = *(const floatx4*)(np0 + 4);
            n2 = *(const floatx4*)(np1);
            n3 = *(const floatx4*)(np1 + 4);
        }

        H8 bf0, bf1;
        bf0.u[0] = pkrtz(a0[0], a0[1]);  bf0.u[1] = pkrtz(a0[2], a0[3]);
        bf0.u[2] = pkrtz(a1[0], a1[1]);  bf0.u[3] = pkrtz(a1[2], a1[3]);
        bf1.u[0] = pkrtz(a2[0], a2[1]);  bf1.u[1] = pkrtz(a2[2], a2[3]);
        bf1.u[2] = pkrtz(a3[0], a3[1]);  bf1.u[3] = pkrtz(a3[2], a3[3]);

        H8 w1v, b1v;
        w1v.v8 = *(const halfx8*)(w1s + i * H_ + koff);
        b1v.v8 = *(const halfx8*)(b1s + i * H_ + koff);

        // per-k constants from LDS: {lw*w3, b2} f16 pairs (broadcast reads)
        halfx2 q0 = __builtin_bit_cast(halfx2, wbs[i * H_ + col]);
        halfx2 q1 = __builtin_bit_cast(halfx2, wbs[i * H_ + col + 16]);
        float w3e0 = (float)q0[0], b2c0 = (float)q0[1];
        float w3e1 = (float)q1[0], b2c1 = (float)q1[1];
        float p0 = 0.505f * w3e0, nn0 = 0.495f * w3e0;  // leaky decomposition
        float p1 = 0.505f * w3e1, nn1 = 0.495f * w3e1;

        #pragma unroll
        for (int m = 0; m < MT; ++m) {
            halfx2 xx = __builtin_bit_cast(halfx2, xsp[(m * 16 + col) * XSTR + i]);
            H8 af;
            #pragma unroll
            for (int j = 0; j < 4; ++j) {
                halfx2 h = __builtin_elementwise_fma(xx, w1v.v2[j], b1v.v2[j]);
                af.v2[j] = __builtin_elementwise_max(h, h * slope);  // pk leaky
            }
            floatx4 c0 = { b2c0, b2c0, b2c0, b2c0 };   // b2 folded into C
            floatx4 c1 = { b2c1, b2c1, b2c1, b2c1 };
            c0 = __builtin_amdgcn_mfma_f32_16x16x32_f16(af.v8, bf0.v8, c0, 0, 0, 0);
            c1 = __builtin_amdgcn_mfma_f32_16x16x32_f16(af.v8, bf1.v8, c1, 0, 0, 0);
            // pacc += leaky(c)*w3e : leaky(v)*w = (.505w)*v + (.495w)*|v|
            #pragma unroll
            for (int r = 0; r < 4; ++r) {
                float acc = pacc[m][r];
                acc = fmaf(p0,  c0[r],
                      fmaf(nn0, fabsf(c0[r]),
                      fmaf(p1,  c1[r],
                      fmaf(nn1, fabsf(c1[r]), acc))));
                pacc[m][r] = acc;
            }
        }

        a0 = n0; a1 = n1; a2 = n2; a3 = n3;
    }

    // ---- in-wave reduce over the 16 col lanes, deposit i-slice partials ----
    #pragma unroll
    for (int m = 0; m < MT; ++m) {
        #pragma unroll
        for (int r = 0; r < 4; ++r) {
            float v = pacc[m][r];
            v += __shfl_xor(v, 1, 64);
            v += __shfl_xor(v, 2, 64);
            v += __shfl_xor(v, 4, 64);
            v += __shfl_xor(v, 8, 64);
            if (col == 0)
                part[wave][m * 16 + kh * 4 + r] = v;   // C row = (lane>>4)*4+reg
        }
    }
    __syncthreads();

    // ---- cross-wave sum + per-row constant, write out[b,o] ----
    if (t < ROWS) {
        float v = rc[t];
        #pragma unroll
        for (int w = 0; w < NWAVE; ++w) v += part[w][t];
        out[(size_t)(row0 + t) * NO + o] = v;
    }
}

extern "C" void kernel_launch(void* const* d_in, const int* in_sizes, int n_in,
                              void* d_out, int out_size, void* d_ws, size_t ws_size,
                              hipStream_t stream) {
    const float* x  = (const float*)d_in[0];
    const float* W1 = (const float*)d_in[1];
    const float* b1 = (const float*)d_in[2];
    const float* W2 = (const float*)d_in[3];
    const float* b2 = (const float*)d_in[4];
    const float* W3 = (const float*)d_in[5];
    const float* b3 = (const float*)d_in[6];
    const float* lw = (const float*)d_in[7];
    const float* bw = (const float*)d_in[8];
    float* out = (float*)d_out;

    dim3 grid(NO, NB / ROWS);   // 512 blocks, o fastest (XCD-local W2), 2/CU
    kan_kernel<<<grid, dim3(512), 0, stream>>>(x, W1, b1, W2, b2, W3, b3, lw, bw, out);
}

// Round 12
// 111.192 us; speedup vs baseline: 1.1273x; 1.0308x over previous
//
#include <hip/hip_runtime.h>

// KANLayer: B=1024, I=64, O=64, H=32. ALL I/O float32 (per reference).
// out[b,o] = sum_i [ bw[o,i]*leaky(x[b,i]) + lw[o,i]*( sum_k W3[o,i,k]*h2[k] + b3[o,i] ) ]
//   h1[h] = leaky(x[b,i]*W1[o,i,h] + b1[o,i,h])
//   h2[k] = leaky(sum_h h1[h]*W2[o,i,k,h] + b2[o,i,k])
//
// R12 = R11's experiment run WITHOUT spills. 256-thread blocks (4 waves,
// the allocator regime that has never spilled; wg=512 spilled twice),
// ROWS=128, MT=8 m-tiles/wave, wave w owns i-slice [w*16,w*16+16).
// Frag-iters/CU = 128 (R11 level), 16 MFMA per W2 fragment. One-iter W2
// register prefetch. rc row-constant loop moved AFTER the main loop so its
// dependent-load chain doesn't head-serialize waves 0-1 against the final
// barrier. launch_bounds(256,4): VGPR budget 128, est. use ~90.
// Grid 512 blocks (o-fastest, XCD-local W2) = 2/CU. LDS 51.5 KB.
// mfma_f32_16x16x32_f16, f32 accum, b2 folded into C, epilogue leaky via
// abs-modifier identity (leaky(v)*w = .505w*v + .495w*|v|).

#define H_   32
#define NI   64
#define NO   64
#define NB   1024
#define ROWS 128    // batch rows per block (8 m-tiles)
#define MT   8      // m-tiles per wave
#define XSTR 66     // x LDS row stride (uint pairs): 8B-aligned, 2-way banks (free)
#define NWAVE 4

typedef float    floatx4 __attribute__((ext_vector_type(4)));
typedef _Float16 halfx8  __attribute__((ext_vector_type(8)));
typedef _Float16 halfx2  __attribute__((ext_vector_type(2)));

union H8 { halfx8 v8; halfx2 v2[4]; unsigned int u[4]; };

__device__ inline float leaky(float v) { return fmaxf(v, 0.01f * v); }

__device__ inline unsigned int pkrtz(float a, float b) {   // (a,b) -> f16x2, RTZ
    return __builtin_bit_cast(unsigned int, __builtin_amdgcn_cvt_pkrtz(a, b));
}

__global__ __launch_bounds__(256, 4)
void kan_kernel(const float* __restrict__ x,  const float* __restrict__ W1,
                const float* __restrict__ b1, const float* __restrict__ W2,
                const float* __restrict__ b2, const float* __restrict__ W3,
                const float* __restrict__ b3, const float* __restrict__ lw,
                const float* __restrict__ bw, float* __restrict__ out)
{
    __shared__ unsigned int xsp[ROWS * XSTR];  // x dup-f16 pairs, 33 KB
    __shared__ _Float16 w1s[NI * H_];          // 4 KB
    __shared__ _Float16 b1s[NI * H_];          // 4 KB
    __shared__ unsigned int wbs[NI * H_];      // {lw*w3, b2} f16 pairs, 8 KB
    __shared__ float rc[ROWS];                 // 512 B
    __shared__ float part[NWAVE][ROWS];        // per-wave i-slice partials, 2 KB

    const int t    = threadIdx.x;
    const int o    = blockIdx.x;               // o fastest -> same-o blocks share XCD
    const int row0 = blockIdx.y * ROWS;

    // ---- stage x tile as duplicated f16 pairs (256 thr x 32 floats) ----
    const float* xsrc = x + (size_t)row0 * NI;
    #pragma unroll
    for (int v = 0; v < 8; ++v) {
        int fe = (v * 256 + t) * 4;            // multiple of 4
        int r = fe >> 6, c = fe & 63;
        float4 xv = *(const float4*)(xsrc + fe);
        uint2 lo = { pkrtz(xv.x, xv.x), pkrtz(xv.y, xv.y) };
        uint2 hi = { pkrtz(xv.z, xv.z), pkrtz(xv.w, xv.w) };
        *(uint2*)(&xsp[r * XSTR + c])     = lo;   // 66r+c even -> 8B aligned
        *(uint2*)(&xsp[r * XSTR + c + 2]) = hi;
    }
    // ---- stage W1/b1 for this o as f16 (256 thr x 2 passes of 4) ----
    const float* w1g = W1 + (size_t)o * NI * H_;
    const float* b1g = b1 + (size_t)o * NI * H_;
    #pragma unroll
    for (int v = 0; v < 2; ++v) {
        int e = (v * 256 + t) * 4;
        float4 a = *(const float4*)(w1g + e);
        float4 c = *(const float4*)(b1g + e);
        uint2 pa = { pkrtz(a.x, a.y), pkrtz(a.z, a.w) };
        uint2 pc = { pkrtz(c.x, c.y), pkrtz(c.z, c.w) };
        *(uint2*)(w1s + e) = pa;
        *(uint2*)(b1s + e) = pc;
    }
    // ---- stage {lw*w3, b2} pairs: 2048 entries, 8 per thread ----
    {
        int e = t * 8;                          // i = e>>5, k = e&31 .. +7
        float l = lw[o * NI + (e >> 5)];
        const float* w3g = W3 + (size_t)o * NI * H_ + e;
        const float* b2g = b2 + (size_t)o * NI * H_ + e;
        float4 wa = *(const float4*)(w3g), wb = *(const float4*)(w3g + 4);
        float4 ba = *(const float4*)(b2g), bb = *(const float4*)(b2g + 4);
        uint4 p0 = { pkrtz(l * wa.x, ba.x), pkrtz(l * wa.y, ba.y),
                     pkrtz(l * wa.z, ba.z), pkrtz(l * wa.w, ba.w) };
        uint4 p1 = { pkrtz(l * wb.x, bb.x), pkrtz(l * wb.y, bb.y),
                     pkrtz(l * wb.z, bb.z), pkrtz(l * wb.w, bb.w) };
        *(uint4*)(&wbs[e])     = p0;
        *(uint4*)(&wbs[e + 4]) = p1;
    }
    __syncthreads();

    const int lane = t & 63, wave = t >> 6;
    const int col  = lane & 15;            // MFMA n-index (h2 k-slot) / A m-offset
    const int kh   = lane >> 4;            // contraction quad
    const int koff = kh * 8;
    const int i0   = wave * 16;            // this wave's i-slice (16 wide)

    const float* w2p0 = W2 + ((size_t)(o * NI + i0) * H_ + col) * H_ + koff;
    const float* w2p1 = w2p0 + 16 * H_;
    const halfx2 slope = { (_Float16)0.01f, (_Float16)0.01f };

    floatx4 pacc[MT];
    #pragma unroll
    for (int m = 0; m < MT; ++m)
        pacc[m] = floatx4{0.f, 0.f, 0.f, 0.f};

    // prime the prefetch registers with iter 0's W2 fragment
    floatx4 a0 = *(const floatx4*)(w2p0);
    floatx4 a1 = *(const floatx4*)(w2p0 + 4);
    floatx4 a2 = *(const floatx4*)(w2p1);
    floatx4 a3 = *(const floatx4*)(w2p1 + 4);

    #pragma unroll 2
    for (int ii = 0; ii < 16; ++ii) {
        const int i = i0 + ii;

        // issue next iteration's W2 loads before consuming this one's
        floatx4 n0, n1, n2, n3;
        if (ii < 15) {
            const float* np0 = w2p0 + (ii + 1) * (H_ * H_);
            const float* np1 = w2p1 + (ii + 1) * (H_ * H_);
            n0 = *(const floatx4*)(np0);
            n1 = *(const floatx4*)(np0 + 4);
            n2 = *(const floatx4*)(np1);
            n3 = *(const floatx4*)(np1 + 4);
        }

        H8 bf0, bf1;
        bf0.u[0] = pkrtz(a0[0], a0[1]);  bf0.u[1] = pkrtz(a0[2], a0[3]);
        bf0.u[2] = pkrtz(a1[0], a1[1]);  bf0.u[3] = pkrtz(a1[2], a1[3]);
        bf1.u[0] = pkrtz(a2[0], a2[1]);  bf1.u[1] = pkrtz(a2[2], a2[3]);
        bf1.u[2] = pkrtz(a3[0], a3[1]);  bf1.u[3] = pkrtz(a3[2], a3[3]);

        H8 w1v, b1v;
        w1v.v8 = *(const halfx8*)(w1s + i * H_ + koff);
        b1v.v8 = *(const halfx8*)(b1s + i * H_ + koff);

        // per-k constants from LDS: {lw*w3, b2} f16 pairs (broadcast reads)
        halfx2 q0 = __builtin_bit_cast(halfx2, wbs[i * H_ + col]);
        halfx2 q1 = __builtin_bit_cast(halfx2, wbs[i * H_ + col + 16]);
        float w3e0 = (float)q0[0], b2c0 = (float)q0[1];
        float w3e1 = (float)q1[0], b2c1 = (float)q1[1];
        float p0 = 0.505f * w3e0, nn0 = 0.495f * w3e0;  // leaky decomposition
        float p1 = 0.505f * w3e1, nn1 = 0.495f * w3e1;

        #pragma unroll
        for (int m = 0; m < MT; ++m) {
            halfx2 xx = __builtin_bit_cast(halfx2, xsp[(m * 16 + col) * XSTR + i]);
            H8 af;
            #pragma unroll
            for (int j = 0; j < 4; ++j) {
                halfx2 h = __builtin_elementwise_fma(xx, w1v.v2[j], b1v.v2[j]);
                af.v2[j] = __builtin_elementwise_max(h, h * slope);  // pk leaky
            }
            floatx4 c0 = { b2c0, b2c0, b2c0, b2c0 };   // b2 folded into C
            floatx4 c1 = { b2c1, b2c1, b2c1, b2c1 };
            c0 = __builtin_amdgcn_mfma_f32_16x16x32_f16(af.v8, bf0.v8, c0, 0, 0, 0);
            c1 = __builtin_amdgcn_mfma_f32_16x16x32_f16(af.v8, bf1.v8, c1, 0, 0, 0);
            // pacc += leaky(c)*w3e : leaky(v)*w = (.505w)*v + (.495w)*|v|
            #pragma unroll
            for (int r = 0; r < 4; ++r) {
                float acc = pacc[m][r];
                acc = fmaf(p0,  c0[r],
                      fmaf(nn0, fabsf(c0[r]),
                      fmaf(p1,  c1[r],
                      fmaf(nn1, fabsf(c1[r]), acc))));
                pacc[m][r] = acc;
            }
        }

        a0 = n0; a1 = n1; a2 = n2; a3 = n3;
    }

    // ---- in-wave reduce over the 16 col lanes, deposit i-slice partials ----
    #pragma unroll
    for (int m = 0; m < MT; ++m) {
        #pragma unroll
        for (int r = 0; r < 4; ++r) {
            float v = pacc[m][r];
            v += __shfl_xor(v, 1, 64);
            v += __shfl_xor(v, 2, 64);
            v += __shfl_xor(v, 4, 64);
            v += __shfl_xor(v, 8, 64);
            if (col == 0)
                part[wave][m * 16 + kh * 4 + r] = v;   // C row = (lane>>4)*4+reg
        }
    }

    // ---- per-row constants (AFTER main loop: no head-of-kernel serial lag)
    if (t < ROWS) {
        float s = 0.f;
        const float* bwp = bw + o * NI;
        const float* lp  = lw + o * NI;
        const float* b3p = b3 + o * NI;
        for (int i = 0; i < NI; ++i) {
            halfx2 hx = __builtin_bit_cast(halfx2, xsp[t * XSTR + i]);
            s += bwp[i] * leaky((float)hx[0]) + lp[i] * b3p[i];
        }
        rc[t] = s;
    }
    __syncthreads();

    // ---- cross-wave sum + per-row constant, write out[b,o] ----
    if (t < ROWS) {
        float v = rc[t];
        #pragma unroll
        for (int w = 0; w < NWAVE; ++w) v += part[w][t];
        out[(size_t)(row0 + t) * NO + o] = v;
    }
}

extern "C" void kernel_launch(void* const* d_in, const int* in_sizes, int n_in,
                              void* d_out, int out_size, void* d_ws, size_t ws_size,
                              hipStream_t stream) {
    const float* x  = (const float*)d_in[0];
    const float* W1 = (const float*)d_in[1];
    const float* b1 = (const float*)d_in[2];
    const float* W2 = (const float*)d_in[3];
    const float* b2 = (const float*)d_in[4];
    const float* W3 = (const float*)d_in[5];
    const float* b3 = (const float*)d_in[6];
    const float* lw = (const float*)d_in[7];
    const float* bw = (const float*)d_in[8];
    float* out = (float*)d_out;

    dim3 grid(NO, NB / ROWS);   // 512 blocks, o fastest (XCD-local W2), 2/CU
    kan_kernel<<<grid, dim3(256), 0, stream>>>(x, W1, b1, W2, b2, W3, b3, lw, bw, out);
}